// Round 6
// baseline (315.115 us; speedup 1.0000x reference)
//
#include <hip/hip_runtime.h>

// Problem constants (reference: Q=2048, N=32768, D=512, C=100)
#define QN 2048
#define NN 32768
#define DD 512
#define CC 100
#define MAXTILES 356            // sum ceil(n_c/128) <= 256 + 100
#define MAXNP (MAXTILES * 128)  // 45568 max padded columns

typedef float f32x4 __attribute__((ext_vector_type(4)));
typedef __bf16 bf16x8 __attribute__((ext_vector_type(8)));
typedef unsigned short u16x8 __attribute__((ext_vector_type(8)));

// meta layout (int32 indices within first 4 KiB of ws)
#define M_HIST 0    // [100] class histogram
#define M_FILL 128  // [100] scatter fill counters
#define M_SEG 256   // [101] padded start column per class
#define M_TC 384    // [356] class of each 128-col tile
#define M_NT 768    // number of 128-col tiles
#define M_NCOL 769  // total padded columns

// ws byte offsets
#define OFF_X2 4096
#define OFF_DB2 16384
#define OFF_MIN 262144
#define OFF_XB (1u << 21)
#define OFF_DBS (1u << 22)

__device__ __forceinline__ unsigned short f2bf(float f) {
  unsigned u = __float_as_uint(f);
  unsigned r = 0x7FFFu + ((u >> 16) & 1u);  // round-to-nearest-even
  return (unsigned short)((u + r) >> 16);
}

typedef const __attribute__((address_space(1))) void* gptr_t;
typedef __attribute__((address_space(3))) void* lptr_t;
__device__ __forceinline__ void gload_lds16(const void* g, void* l) {
  __builtin_amdgcn_global_load_lds((gptr_t)g, (lptr_t)l, 16, 0, 0);
}

// ---- class histogram (LDS-local then one flush per block) ----
__global__ void k_hist(const int* __restrict__ labels, int* __restrict__ meta) {
  __shared__ int h[CC];
  int t = threadIdx.x;
  if (t < CC) h[t] = 0;
  __syncthreads();
#pragma unroll
  for (int i = 0; i < 4; ++i) {
    int n = blockIdx.x * 1024 + i * 256 + t;
    atomicAdd(&h[labels[n]], 1);
  }
  __syncthreads();
  if (t < CC) atomicAdd(&meta[M_HIST + t], h[t]);
}

// ---- scan over 100 classes (serial part on LDS, writes parallel) ----
__global__ void k_scan(int* __restrict__ meta) {
  __shared__ int h[CC], seg[CC + 1], tile0[CC];
  int t = threadIdx.x;
  for (int c = t; c < CC; c += 128) h[c] = meta[M_HIST + c];
  __syncthreads();
  if (t == 0) {
    int col = 0, nt = 0;
    for (int c = 0; c < CC; ++c) {
      seg[c] = col;
      tile0[c] = nt;
      int tiles = (h[c] + 127) >> 7;
      nt += tiles;
      col += tiles << 7;
    }
    seg[CC] = col;
    meta[M_NT] = nt;
    meta[M_NCOL] = col;
    meta[M_SEG + CC] = col;
  }
  __syncthreads();
  for (int c = t; c < CC; c += 128) {
    meta[M_SEG + c] = seg[c];
    int tiles = (h[c] + 127) >> 7;
    int t0 = tile0[c];
    for (int i = 0; i < tiles; ++i) meta[M_TC + t0 + i] = c;
  }
}

// ---- x: fp32 -> bf16 + row sumsq. One wave per row. ----
__global__ void k_prep_x(const float* __restrict__ x, unsigned short* __restrict__ xb,
                         float* __restrict__ x2) {
  int w = threadIdx.x >> 6, lane = threadIdx.x & 63;
  int q = blockIdx.x * 4 + w;
  const float4* row = (const float4*)(x + (size_t)q * DD);
  float4 v0 = row[lane * 2];
  float4 v1 = row[lane * 2 + 1];
  float s = v0.x * v0.x + v0.y * v0.y + v0.z * v0.z + v0.w * v0.w +
            v1.x * v1.x + v1.y * v1.y + v1.z * v1.z + v1.w * v1.w;
  u16x8 o;
  o[0] = f2bf(v0.x); o[1] = f2bf(v0.y); o[2] = f2bf(v0.z); o[3] = f2bf(v0.w);
  o[4] = f2bf(v1.x); o[5] = f2bf(v1.y); o[6] = f2bf(v1.z); o[7] = f2bf(v1.w);
  ((u16x8*)(xb + (size_t)q * DD))[lane] = o;
#pragma unroll
  for (int m = 32; m; m >>= 1) s += __shfl_xor(s, m);
  if (lane == 0) x2[q] = s;
}

// ---- scatter + pad-fill + min-init, one kernel (independent branches) ----
__global__ void k_spi(const float* __restrict__ db, const int* __restrict__ labels,
                      int* __restrict__ meta, unsigned short* __restrict__ dbs,
                      float* __restrict__ db2s, unsigned* __restrict__ mb) {
  int b = blockIdx.x, t = threadIdx.x;
  if (b < (QN * CC) / 256) mb[b * 256 + t] = 0x7F800000u;  // +inf bits
  int w = t >> 6, lane = t & 63;
  if (b < NN / 4) {
    int n = b * 4 + w;
    int c = labels[n];
    int pos = 0;
    if (lane == 0) pos = meta[M_SEG + c] + atomicAdd(&meta[M_FILL + c], 1);
    pos = __shfl(pos, 0);
    const float4* row = (const float4*)(db + (size_t)n * DD);
    float4 v0 = row[lane * 2];
    float4 v1 = row[lane * 2 + 1];
    float s = v0.x * v0.x + v0.y * v0.y + v0.z * v0.z + v0.w * v0.w +
              v1.x * v1.x + v1.y * v1.y + v1.z * v1.z + v1.w * v1.w;
    u16x8 o;
    o[0] = f2bf(v0.x); o[1] = f2bf(v0.y); o[2] = f2bf(v0.z); o[3] = f2bf(v0.w);
    o[4] = f2bf(v1.x); o[5] = f2bf(v1.y); o[6] = f2bf(v1.z); o[7] = f2bf(v1.w);
    ((u16x8*)(dbs + (size_t)pos * DD))[lane] = o;
#pragma unroll
    for (int m = 32; m; m >>= 1) s += __shfl_xor(s, m);
    if (lane == 0) db2s[pos] = s;
  } else {
    int p = (b - NN / 4) * 4 + w;
    if (p >= meta[M_NCOL]) return;
    int c = meta[M_TC + (p >> 7)];
    if (p - meta[M_SEG + c] < meta[M_HIST + c]) return;  // real row, written by scatter
    u16x8 z = {0, 0, 0, 0, 0, 0, 0, 0};
    ((u16x8*)(dbs + (size_t)p * DD))[lane] = z;
    if (lane == 0) db2s[p] = __builtin_inff();
  }
}

// ---- fused bf16 MFMA GEMM + per-class row-min ----
// 128x128 tile, BK=32, 4 waves (2x2), 4 LDS K-buffers (64 KiB -> 2 blk/CU).
// Counted-vmcnt pipeline, fully unrolled K (16 steps) so ALL buffer indices
// are literals: provably-disjoint LDS offsets (no compiler auto-drain), no
// sched_barrier / lgkmcnt pins (compiler fine-schedules ds_read vs MFMA).
// One raw s_barrier per step: releases buffer (kt-1)&3 for staging AND
// publishes tile kt (each wave's own loads forced done by the vmcnt before).
__launch_bounds__(256, 2)
__global__ void k_gemm(const unsigned short* __restrict__ xb,
                       const unsigned short* __restrict__ dbs,
                       const float* __restrict__ x2, const float* __restrict__ db2s,
                       const int* __restrict__ meta, unsigned* __restrict__ minbits) {
  // XCD-aware bijective remap: 16 x 356 = 5696 blocks, 712 per XCD chunk.
  int flat = blockIdx.y * 16 + blockIdx.x;
  int swz = (flat & 7) * (16 * MAXTILES / 8) + (flat >> 3);
  int tq = swz & 15, tn = swz >> 4;
  if (tn >= meta[M_NT]) return;
  int cls = meta[M_TC + tn];

  __shared__ __align__(16) unsigned short SA[4][128 * 32];  // 32 KiB
  __shared__ __align__(16) unsigned short SB[4][128 * 32];  // 32 KiB

  int t = threadIdx.x;
  int lane = t & 63;
  int wid = t >> 6;
  int wm = wid >> 1, wn = wid & 1;  // 2x2 waves of 64x64
  int cl = lane & 15, g = lane >> 4;

  // staging: thread t -> rows (t>>2) and 64+(t>>2), physical slot t&3.
  // global granule pre-unswizzled: logical = (t&3) ^ ((R>>1)&3) = (t&3)^((t>>3)&3)
  int gsrc = (t & 3) ^ ((t >> 3) & 3);
  const unsigned short* Ag = xb + ((size_t)tq * 128 + (t >> 2)) * DD + gsrc * 8;
  const unsigned short* Bg = dbs + ((size_t)tn * 128 + (t >> 2)) * DD + gsrc * 8;

  // read offsets (shorts), swizzled: phys_slot = g ^ ((R>>1)&3)
  int offA[4], offB[4];
#pragma unroll
  for (int m = 0; m < 4; ++m) {
    int R = wm * 64 + m * 16 + cl;
    offA[m] = R * 32 + ((g ^ ((R >> 1) & 3)) * 8);
  }
#pragma unroll
  for (int n = 0; n < 4; ++n) {
    int R = wn * 64 + n * 16 + cl;
    offB[n] = R * 32 + ((g ^ ((R >> 1) & 3)) * 8);
  }

  f32x4 acc[4][4];
#pragma unroll
  for (int m = 0; m < 4; ++m)
#pragma unroll
    for (int n = 0; n < 4; ++n) acc[m][n] = (f32x4){0.f, 0.f, 0.f, 0.f};

#define STAGE(BUF, TILE)                                             \
  gload_lds16(Ag + (TILE) * 32, &SA[BUF][t * 8]);                    \
  gload_lds16(Ag + 64 * DD + (TILE) * 32, &SA[BUF][2048 + t * 8]);   \
  gload_lds16(Bg + (TILE) * 32, &SB[BUF][t * 8]);                    \
  gload_lds16(Bg + 64 * DD + (TILE) * 32, &SB[BUF][2048 + t * 8]);

#define COMPUTE(BUF)                                                          \
  {                                                                           \
    bf16x8 av[4], bv[4];                                                      \
    _Pragma("unroll") for (int n = 0; n < 4; ++n) bv[n] =                     \
        *(const bf16x8*)(&SB[BUF][offB[n]]);                                  \
    _Pragma("unroll") for (int m = 0; m < 4; ++m) av[m] =                     \
        *(const bf16x8*)(&SA[BUF][offA[m]]);                                  \
    _Pragma("unroll") for (int m = 0; m < 4; ++m)                             \
        _Pragma("unroll") for (int n = 0; n < 4; ++n) acc[m][n] =             \
            __builtin_amdgcn_mfma_f32_16x16x32_bf16(av[m], bv[n], acc[m][n],  \
                                                    0, 0, 0);                 \
  }

#define STEP_S(CB, SB_, TILE, VM)                          \
  asm volatile("s_waitcnt vmcnt(" #VM ")" ::: "memory");   \
  __builtin_amdgcn_s_barrier();                            \
  asm volatile("" ::: "memory");                           \
  STAGE(SB_, TILE)                                         \
  COMPUTE(CB)

#define STEP_N(CB, VM)                                     \
  asm volatile("s_waitcnt vmcnt(" #VM ")" ::: "memory");   \
  __builtin_amdgcn_s_barrier();                            \
  asm volatile("" ::: "memory");                           \
  COMPUTE(CB)

  STAGE(0, 0)
  STAGE(1, 1)
  STAGE(2, 2)

  STEP_S(0, 3, 3, 8)    // kt=0
  STEP_S(1, 0, 4, 8)    // kt=1
  STEP_S(2, 1, 5, 8)    // kt=2
  STEP_S(3, 2, 6, 8)    // kt=3
  STEP_S(0, 3, 7, 8)    // kt=4
  STEP_S(1, 0, 8, 8)    // kt=5
  STEP_S(2, 1, 9, 8)    // kt=6
  STEP_S(3, 2, 10, 8)   // kt=7
  STEP_S(0, 3, 11, 8)   // kt=8
  STEP_S(1, 0, 12, 8)   // kt=9
  STEP_S(2, 1, 13, 8)   // kt=10
  STEP_S(3, 2, 14, 8)   // kt=11
  STEP_S(0, 3, 15, 8)   // kt=12
  STEP_N(1, 8)          // kt=13
  STEP_N(2, 4)          // kt=14
  STEP_N(3, 0)          // kt=15

#undef STEP_S
#undef STEP_N
#undef STAGE
#undef COMPUTE

  // Epilogue: whole block is one class. d2 = x2[q] + min_n(db2[n] - 2*dot).
  float db2v[4];
#pragma unroll
  for (int n = 0; n < 4; ++n) db2v[n] = db2s[tn * 128 + wn * 64 + n * 16 + cl];

#pragma unroll
  for (int m = 0; m < 4; ++m) {
    int rowb = tq * 128 + wm * 64 + m * 16 + g * 4;
#pragma unroll
    for (int r = 0; r < 4; ++r) {
      float v = db2v[0] - 2.0f * acc[m][0][r];
      v = fminf(v, db2v[1] - 2.0f * acc[m][1][r]);
      v = fminf(v, db2v[2] - 2.0f * acc[m][2][r]);
      v = fminf(v, db2v[3] - 2.0f * acc[m][3][r]);
#pragma unroll
      for (int s = 1; s < 16; s <<= 1) v = fminf(v, __shfl_xor(v, s));
      if (cl == 0) {
        float d = sqrtf(fmaxf(x2[rowb + r] + v, 0.0f));
        atomicMin(minbits + (size_t)(rowb + r) * CC + cls, __float_as_uint(d));
      }
    }
  }
}

__global__ void k_final(const unsigned* __restrict__ mb, float* __restrict__ out) {
  int i = blockIdx.x * 256 + threadIdx.x;
  if (i < QN * CC) out[i] = -__uint_as_float(mb[i]);
}

extern "C" void kernel_launch(void* const* d_in, const int* in_sizes, int n_in,
                              void* d_out, int out_size, void* d_ws, size_t ws_size,
                              hipStream_t stream) {
  (void)in_sizes; (void)n_in; (void)out_size; (void)ws_size;
  const float* x = (const float*)d_in[0];
  const float* db = (const float*)d_in[1];
  const int* labels = (const int*)d_in[2];

  char* ws = (char*)d_ws;
  int* meta = (int*)ws;
  float* x2 = (float*)(ws + OFF_X2);
  float* db2s = (float*)(ws + OFF_DB2);
  unsigned* minbits = (unsigned*)(ws + OFF_MIN);
  unsigned short* xb = (unsigned short*)(ws + OFF_XB);
  unsigned short* dbs = (unsigned short*)(ws + OFF_DBS);

  hipMemsetAsync(ws, 0, 4096, stream);
  k_hist<<<NN / 1024, 256, 0, stream>>>(labels, meta);
  k_scan<<<1, 128, 0, stream>>>(meta);
  k_prep_x<<<QN / 4, 256, 0, stream>>>(x, xb, x2);
  k_spi<<<NN / 4 + MAXNP / 4, 256, 0, stream>>>(db, labels, meta, dbs, db2s, minbits);
  k_gemm<<<dim3(16, MAXTILES), 256, 0, stream>>>(xb, dbs, x2, db2s, meta, minbits);
  k_final<<<(QN * CC + 255) / 256, 256, 0, stream>>>(minbits, (float*)d_out);
}

// Round 7
// 310.546 us; speedup vs baseline: 1.0147x; 1.0147x over previous
//
#include <hip/hip_runtime.h>

// Problem constants (reference: Q=2048, N=32768, D=512, C=100)
#define QN 2048
#define NN 32768
#define DD 512
#define CC 100
#define MAXTILES 356            // sum ceil(n_c/128) <= 256 + 100
#define MAXNP (MAXTILES * 128)  // 45568 max padded columns
#define NT256 (MAXTILES / 2)    // 178 max 256-col tiles

typedef float f32x4 __attribute__((ext_vector_type(4)));
typedef __bf16 bf16x8 __attribute__((ext_vector_type(8)));
typedef unsigned short u16x8 __attribute__((ext_vector_type(8)));

// meta layout (int32 indices within first 4 KiB of ws)
#define M_HIST 0    // [100] class histogram
#define M_FILL 128  // [100] scatter fill counters
#define M_SEG 256   // [101] padded start column per class
#define M_TC 384    // [356] class of each 128-col tile (0 beyond NT via memset)
#define M_NT 768    // number of 128-col tiles
#define M_NCOL 769  // padded columns rounded up to 256-multiple

// ws byte offsets
#define OFF_X2 4096
#define OFF_DB2 16384
#define OFF_MIN 262144
#define OFF_XB (1u << 21)
#define OFF_DBS (1u << 22)

__device__ __forceinline__ unsigned short f2bf(float f) {
  unsigned u = __float_as_uint(f);
  unsigned r = 0x7FFFu + ((u >> 16) & 1u);  // round-to-nearest-even
  return (unsigned short)((u + r) >> 16);
}

typedef const __attribute__((address_space(1))) void* gptr_t;
typedef __attribute__((address_space(3))) void* lptr_t;
__device__ __forceinline__ void gload_lds16(const void* g, void* l) {
  __builtin_amdgcn_global_load_lds((gptr_t)g, (lptr_t)l, 16, 0, 0);
}

// ---- x: fp32 -> bf16 + row sumsq (blocks < QN/4); class hist (last 32) ----
__global__ void k_prep(const float* __restrict__ x, const int* __restrict__ labels,
                       unsigned short* __restrict__ xb, float* __restrict__ x2,
                       int* __restrict__ meta) {
  __shared__ int h[CC];
  int b = blockIdx.x, t = threadIdx.x;
  if (b >= QN / 4) {  // histogram part
    int bb = b - QN / 4;
    if (t < CC) h[t] = 0;
    __syncthreads();
#pragma unroll
    for (int i = 0; i < 4; ++i) atomicAdd(&h[labels[bb * 1024 + i * 256 + t]], 1);
    __syncthreads();
    if (t < CC) atomicAdd(&meta[M_HIST + t], h[t]);
    return;
  }
  int w = t >> 6, lane = t & 63;
  int q = b * 4 + w;
  const float4* row = (const float4*)(x + (size_t)q * DD);
  float4 v0 = row[lane * 2];
  float4 v1 = row[lane * 2 + 1];
  float s = v0.x * v0.x + v0.y * v0.y + v0.z * v0.z + v0.w * v0.w +
            v1.x * v1.x + v1.y * v1.y + v1.z * v1.z + v1.w * v1.w;
  u16x8 o;
  o[0] = f2bf(v0.x); o[1] = f2bf(v0.y); o[2] = f2bf(v0.z); o[3] = f2bf(v0.w);
  o[4] = f2bf(v1.x); o[5] = f2bf(v1.y); o[6] = f2bf(v1.z); o[7] = f2bf(v1.w);
  ((u16x8*)(xb + (size_t)q * DD))[lane] = o;
#pragma unroll
  for (int m = 32; m; m >>= 1) s += __shfl_xor(s, m);
  if (lane == 0) x2[q] = s;
}

// ---- scan over 100 classes (serial part on LDS, writes parallel) ----
__global__ void k_scan(int* __restrict__ meta) {
  __shared__ int h[CC], seg[CC + 1], tile0[CC];
  int t = threadIdx.x;
  for (int c = t; c < CC; c += 128) h[c] = meta[M_HIST + c];
  __syncthreads();
  if (t == 0) {
    int col = 0, nt = 0;
    for (int c = 0; c < CC; ++c) {
      seg[c] = col;
      tile0[c] = nt;
      int tiles = (h[c] + 127) >> 7;
      nt += tiles;
      col += tiles << 7;
    }
    seg[CC] = col;
    meta[M_NT] = nt;
    meta[M_NCOL] = ((nt + 1) >> 1) << 8;  // round UP to 256-col multiple
    meta[M_SEG + CC] = col;
  }
  __syncthreads();
  for (int c = t; c < CC; c += 128) {
    meta[M_SEG + c] = seg[c];
    int tiles = (h[c] + 127) >> 7;
    int t0 = tile0[c];
    for (int i = 0; i < tiles; ++i) meta[M_TC + t0 + i] = c;
  }
}

// ---- scatter + pad-fill + min-init, one kernel ----
__global__ void k_spi(const float* __restrict__ db, const int* __restrict__ labels,
                      int* __restrict__ meta, unsigned short* __restrict__ dbs,
                      float* __restrict__ db2s, unsigned* __restrict__ mb) {
  int b = blockIdx.x, t = threadIdx.x;
  if (b < (QN * CC) / 256) mb[b * 256 + t] = 0x7F800000u;  // +inf bits
  int w = t >> 6, lane = t & 63;
  if (b < NN / 4) {
    int n = b * 4 + w;
    int c = labels[n];
    int pos = 0;
    if (lane == 0) pos = meta[M_SEG + c] + atomicAdd(&meta[M_FILL + c], 1);
    pos = __shfl(pos, 0);
    const float4* row = (const float4*)(db + (size_t)n * DD);
    float4 v0 = row[lane * 2];
    float4 v1 = row[lane * 2 + 1];
    float s = v0.x * v0.x + v0.y * v0.y + v0.z * v0.z + v0.w * v0.w +
              v1.x * v1.x + v1.y * v1.y + v1.z * v1.z + v1.w * v1.w;
    u16x8 o;
    o[0] = f2bf(v0.x); o[1] = f2bf(v0.y); o[2] = f2bf(v0.z); o[3] = f2bf(v0.w);
    o[4] = f2bf(v1.x); o[5] = f2bf(v1.y); o[6] = f2bf(v1.z); o[7] = f2bf(v1.w);
    ((u16x8*)(dbs + (size_t)pos * DD))[lane] = o;
#pragma unroll
    for (int m = 32; m; m >>= 1) s += __shfl_xor(s, m);
    if (lane == 0) db2s[pos] = s;
  } else {
    int p = (b - NN / 4) * 4 + w;
    if (p >= meta[M_NCOL]) return;
    int c = meta[M_TC + (p >> 7)];
    if (p - meta[M_SEG + c] < meta[M_HIST + c]) return;  // real row
    u16x8 z = {0, 0, 0, 0, 0, 0, 0, 0};
    ((u16x8*)(dbs + (size_t)p * DD))[lane] = z;
    if (lane == 0) db2s[p] = __builtin_inff();
  }
}

// ---- fused bf16 MFMA GEMM + per-class row-min: m201 256^2 8-phase port ----
// BM=BN=256, BK=64, 8 waves (2Mx4N), LDS 128 KiB: [dbuf][half][128][64] per
// A and B. 8 K-tiles = 8 Phi-blocks x 4 phases. Per phase: ds_read subtile |
// stage 2 quarter-units | barrier | lgkmcnt(0)+sched_barrier | setprio(1)
// 16 MFMA setprio(0) | barrier. Stage stream 1.5 K-tiles ahead; vmcnt(6)
// once per K-tile (never 0 until epilogue). st_16x32 swizzle (granule ^=
// row-bit2) both-sides (rule 21). XCD-chunked remap (T1).
__launch_bounds__(512, 2)
__global__ void k_gemm(const unsigned short* __restrict__ xb,
                       const unsigned short* __restrict__ dbs,
                       const float* __restrict__ x2, const float* __restrict__ db2s,
                       const int* __restrict__ meta, unsigned* __restrict__ minbits) {
  int flat = blockIdx.y * 8 + blockIdx.x;          // 8 x 178 = 1424
  int swz = (flat & 7) * NT256 + (flat >> 3);      // bijective XCD chunks
  int tq = swz & 7, tn = swz >> 3;
  int nt = meta[M_NT];
  if (tn >= ((nt + 1) >> 1)) return;

  __shared__ __align__(16) unsigned short As[2][2][8192];  // [buf][half][128*64]
  __shared__ __align__(16) unsigned short Bs[2][2][8192];

  int t = threadIdx.x;
  int lane = t & 63;
  int wid = t >> 6;
  int wm = wid >> 2, wn = wid & 3;  // per-wave out: 128 x 64
  int cl = lane & 15, g = lane >> 4;

  // staging: thread t -> row t>>3 (0..63) of each 64-row unit, slot t&7.
  // source granule pre-unswizzled: gsrc = slot ^ ((row>>1)&2)   [st_16x32]
  int trow = t >> 3, tslot = t & 7;
  int gsrc = tslot ^ ((t >> 4) & 2);
  const unsigned short* Asrc = xb + ((size_t)(tq * 256 + trow)) * DD + gsrc * 8;
  const unsigned short* Bsrc = dbs + ((size_t)(tn * 256 + trow)) * DD + gsrc * 8;
  int ldst = trow * 64 + tslot * 8;  // shorts within a 64-row unit

  // read swizzle: phys granule = (kh*4+g) ^ ((row>>1)&2), row%16 = cl
  int xsw = (cl >> 1) & 2;
  int gk0 = ((0 + g) ^ xsw) * 8;
  int gk1 = ((4 + g) ^ xsw) * 8;
  int rofsA[8], rofsB[4];
#pragma unroll
  for (int m = 0; m < 8; ++m) rofsA[m] = (m * 16 + cl) * 64;
#pragma unroll
  for (int n = 0; n < 4; ++n) rofsB[n] = ((wn & 1) * 64 + n * 16 + cl) * 64;

  const unsigned short* Ab0 = &As[0][wm][0];
  const unsigned short* Ab1 = &As[1][wm][0];
  const unsigned short* Bb0 = &Bs[0][wn >> 1][0];
  const unsigned short* Bb1 = &Bs[1][wn >> 1][0];

  f32x4 acc[8][4];
#pragma unroll
  for (int m = 0; m < 8; ++m)
#pragma unroll
    for (int n = 0; n < 4; ++n) acc[m][n] = (f32x4){0.f, 0.f, 0.f, 0.f};

  bf16x8 a_[8];  // current A quadrant: [i 0..3][kh]
  bf16x8 b_[8];  // both B pairs:      [n 0..3][kh]

  // unit u: rows 64u..64u+63 -> half u>>1, sub-block u&1
#define STA(b, u, kt)                                                   \
  gload_lds16(Asrc + (size_t)(64 * (u)) * DD + (kt) * 64,               \
              &As[b][(u) >> 1][((u) & 1) * 4096 + ldst]);
#define STB(b, u, kt)                                                   \
  gload_lds16(Bsrc + (size_t)(64 * (u)) * DD + (kt) * 64,               \
              &Bs[b][(u) >> 1][((u) & 1) * 4096 + ldst]);
#define SA13(b, kt) STA(b, 1, kt) STA(b, 3, kt)
#define SA02(b, kt) STA(b, 0, kt) STA(b, 2, kt)
#define SB01(b, kt) STB(b, 0, kt) STB(b, 1, kt)
#define SB23(b, kt) STB(b, 2, kt) STB(b, 3, kt)

#define LDA(AB, MQ)                                                     \
  _Pragma("unroll") for (int i = 0; i < 4; ++i) {                       \
    a_[i * 2 + 0] = *(const bf16x8*)(AB + rofsA[(MQ) * 4 + i] + gk0);   \
    a_[i * 2 + 1] = *(const bf16x8*)(AB + rofsA[(MQ) * 4 + i] + gk1);   \
  }
#define LDB(BB, NP)                                                     \
  _Pragma("unroll") for (int i = 0; i < 2; ++i) {                       \
    b_[((NP) * 2 + i) * 2 + 0] =                                        \
        *(const bf16x8*)(BB + rofsB[(NP) * 2 + i] + gk0);               \
    b_[((NP) * 2 + i) * 2 + 1] =                                        \
        *(const bf16x8*)(BB + rofsB[(NP) * 2 + i] + gk1);               \
  }
#define MM(MQ, NP)                                                      \
  _Pragma("unroll") for (int i = 0; i < 4; ++i)                         \
  _Pragma("unroll") for (int jn = 0; jn < 2; ++jn) {                    \
    acc[(MQ) * 4 + i][(NP) * 2 + jn] =                                  \
        __builtin_amdgcn_mfma_f32_16x16x32_bf16(                        \
            a_[i * 2 + 0], b_[((NP) * 2 + jn) * 2 + 0],                 \
            acc[(MQ) * 4 + i][(NP) * 2 + jn], 0, 0, 0);                 \
    acc[(MQ) * 4 + i][(NP) * 2 + jn] =                                  \
        __builtin_amdgcn_mfma_f32_16x16x32_bf16(                        \
            a_[i * 2 + 1], b_[((NP) * 2 + jn) * 2 + 1],                 \
            acc[(MQ) * 4 + i][(NP) * 2 + jn], 0, 0, 0);                 \
  }
#define TAIL(MQ, NP)                                                    \
  __builtin_amdgcn_s_barrier();                                         \
  asm volatile("s_waitcnt lgkmcnt(0)" ::: "memory");                    \
  __builtin_amdgcn_sched_barrier(0);                                    \
  __builtin_amdgcn_s_setprio(1);                                        \
  MM(MQ, NP)                                                            \
  __builtin_amdgcn_s_setprio(0);                                        \
  __builtin_amdgcn_s_barrier();

#define VM6 asm volatile("s_waitcnt vmcnt(6)" ::: "memory");
#define VM0 asm volatile("s_waitcnt vmcnt(0)" ::: "memory");

  // Phi-block: P1{LDA q0,LDB p0 | S1} P2{LDB p1 | S2A} P3{LDA q1 | S2B01}
  //            P4{S2B23 VM}; quadrant order Q00,Q01,Q11,Q10.
#define PHI(AB_, BB_, S1, S2A, S2B01_, S2B23_, VM)                      \
  LDA(AB_, 0) LDB(BB_, 0) S1 TAIL(0, 0)                                 \
  LDB(BB_, 1) S2A TAIL(0, 1)                                            \
  LDA(AB_, 1) S2B01_ TAIL(1, 1)                                         \
  S2B23_ VM TAIL(1, 0)

  // prologue: tile0 (8 units), tile1 (6 units); confirm tile0.
  SA02(0, 0) SB01(0, 0) SB23(0, 0) SA13(0, 0)
  SA02(1, 1) SB01(1, 1) SB23(1, 1)
  VM6
  __builtin_amdgcn_s_barrier();

  PHI(Ab0, Bb0, SA13(1, 1), SA02(0, 2), SB01(0, 2), SB23(0, 2), VM6)  // kt0
  PHI(Ab1, Bb1, SA13(0, 2), SA02(1, 3), SB01(1, 3), SB23(1, 3), VM6)  // kt1
  PHI(Ab0, Bb0, SA13(1, 3), SA02(0, 4), SB01(0, 4), SB23(0, 4), VM6)  // kt2
  PHI(Ab1, Bb1, SA13(0, 4), SA02(1, 5), SB01(1, 5), SB23(1, 5), VM6)  // kt3
  PHI(Ab0, Bb0, SA13(1, 5), SA02(0, 6), SB01(0, 6), SB23(0, 6), VM6)  // kt4
  PHI(Ab1, Bb1, SA13(0, 6), SA02(1, 7), SB01(1, 7), SB23(1, 7), VM6)  // kt5
  PHI(Ab0, Bb0, SA13(1, 7), , , , VM0)                                 // kt6
  PHI(Ab1, Bb1, , , , , )                                              // kt7

#undef PHI
#undef VM6
#undef VM0
#undef TAIL
#undef MM
#undef LDB
#undef LDA
#undef SA13
#undef SA02
#undef SB01
#undef SB23
#undef STA
#undef STB

  // Epilogue: wave's 64 cols lie in one 128-half => single class.
  int cls = meta[M_TC + tn * 2 + (wn >> 1)];
  float db2v[4];
#pragma unroll
  for (int n = 0; n < 4; ++n) db2v[n] = db2s[tn * 256 + wn * 64 + n * 16 + cl];

#pragma unroll
  for (int m = 0; m < 8; ++m) {
    int rowb = tq * 256 + wm * 128 + m * 16 + g * 4;
#pragma unroll
    for (int r = 0; r < 4; ++r) {
      float v = db2v[0] - 2.0f * acc[m][0][r];
      v = fminf(v, db2v[1] - 2.0f * acc[m][1][r]);
      v = fminf(v, db2v[2] - 2.0f * acc[m][2][r]);
      v = fminf(v, db2v[3] - 2.0f * acc[m][3][r]);
#pragma unroll
      for (int s = 1; s < 16; s <<= 1) v = fminf(v, __shfl_xor(v, s));
      if (cl == 0) {
        float d = sqrtf(fmaxf(x2[rowb + r] + v, 0.0f));
        atomicMin(minbits + (size_t)(rowb + r) * CC + cls, __float_as_uint(d));
      }
    }
  }
}

__global__ void k_final(const unsigned* __restrict__ mb, float* __restrict__ out) {
  int i = blockIdx.x * 256 + threadIdx.x;
  if (i < QN * CC) out[i] = -__uint_as_float(mb[i]);
}

extern "C" void kernel_launch(void* const* d_in, const int* in_sizes, int n_in,
                              void* d_out, int out_size, void* d_ws, size_t ws_size,
                              hipStream_t stream) {
  (void)in_sizes; (void)n_in; (void)out_size; (void)ws_size;
  const float* x = (const float*)d_in[0];
  const float* db = (const float*)d_in[1];
  const int* labels = (const int*)d_in[2];

  char* ws = (char*)d_ws;
  int* meta = (int*)ws;
  float* x2 = (float*)(ws + OFF_X2);
  float* db2s = (float*)(ws + OFF_DB2);
  unsigned* minbits = (unsigned*)(ws + OFF_MIN);
  unsigned short* xb = (unsigned short*)(ws + OFF_XB);
  unsigned short* dbs = (unsigned short*)(ws + OFF_DBS);

  hipMemsetAsync(ws, 0, 4096, stream);
  k_prep<<<QN / 4 + NN / 1024, 256, 0, stream>>>(x, labels, xb, x2, meta);
  k_scan<<<1, 128, 0, stream>>>(meta);
  k_spi<<<NN / 4 + MAXNP / 4, 256, 0, stream>>>(db, labels, meta, dbs, db2s, minbits);
  k_gemm<<<dim3(8, NT256), 512, 0, stream>>>(xb, dbs, x2, db2s, meta, minbits);
  k_final<<<(QN * CC + 255) / 256, 256, 0, stream>>>(minbits, (float*)d_out);
}

// Round 8
// 239.912 us; speedup vs baseline: 1.3135x; 1.2944x over previous
//
#include <hip/hip_runtime.h>

// Problem constants (reference: Q=2048, N=32768, D=512, C=100)
#define QN 2048
#define NN 32768
#define DD 512
#define CC 100
#define MAXTILES 356            // sum ceil(n_c/128) <= 256 + 100
#define MAXNP (MAXTILES * 128)  // 45568 max padded columns
#define NHB 32                  // label histogram blocks (NN/1024)

typedef float f32x4 __attribute__((ext_vector_type(4)));
typedef __bf16 bf16x8 __attribute__((ext_vector_type(8)));
typedef unsigned short u16x8 __attribute__((ext_vector_type(8)));

// meta layout (int32 indices; first 36 KiB of ws)
#define M_HIST 0     // [100] class histogram (atomic-accumulated)
#define M_SEG 128    // [101] padded start column per class
#define M_TC 256     // [356] class of each 128-col tile
#define M_NT 640     // number of 128-col tiles
#define M_NCOL 641   // total padded columns
#define M_BH 1024    // [32][128] per-hist-block class counts
#define M_BB 5120    // [32][128] scatter base = seg[c] + prefix of counts

// ws byte offsets
#define OFF_X2 36864
#define OFF_DB2 45056
#define OFF_MIN 262144
#define OFF_XB (1u << 21)
#define OFF_DBS (1u << 22)

__device__ __forceinline__ unsigned short f2bf(float f) {
  unsigned u = __float_as_uint(f);
  unsigned r = 0x7FFFu + ((u >> 16) & 1u);  // round-to-nearest-even
  return (unsigned short)((u + r) >> 16);
}

typedef const __attribute__((address_space(1))) void* gptr_t;
typedef __attribute__((address_space(3))) void* lptr_t;
__device__ __forceinline__ void gload_lds16(const void* g, void* l) {
  __builtin_amdgcn_global_load_lds((gptr_t)g, (lptr_t)l, 16, 0, 0);
}

// ---- x: fp32->bf16 + row sumsq (blocks < QN/4); label hist (last 32) ----
__global__ void k_prep(const float* __restrict__ x, const int* __restrict__ labels,
                       unsigned short* __restrict__ xb, float* __restrict__ x2,
                       int* __restrict__ meta) {
  __shared__ int h[CC];
  int b = blockIdx.x, t = threadIdx.x;
  if (b >= QN / 4) {  // histogram part: block owns labels[bb*1024 .. +1023]
    int bb = b - QN / 4;
    if (t < CC) h[t] = 0;
    __syncthreads();
#pragma unroll
    for (int i = 0; i < 4; ++i) atomicAdd(&h[labels[bb * 1024 + i * 256 + t]], 1);
    __syncthreads();
    if (t < CC) {
      atomicAdd(&meta[M_HIST + t], h[t]);
      meta[M_BH + bb * 128 + t] = h[t];  // plain store, block owns the row
    }
    return;
  }
  int w = t >> 6, lane = t & 63;
  int q = b * 4 + w;
  const float4* row = (const float4*)(x + (size_t)q * DD);
  float4 v0 = row[lane * 2];
  float4 v1 = row[lane * 2 + 1];
  float s = v0.x * v0.x + v0.y * v0.y + v0.z * v0.z + v0.w * v0.w +
            v1.x * v1.x + v1.y * v1.y + v1.z * v1.z + v1.w * v1.w;
  u16x8 o;
  o[0] = f2bf(v0.x); o[1] = f2bf(v0.y); o[2] = f2bf(v0.z); o[3] = f2bf(v0.w);
  o[4] = f2bf(v1.x); o[5] = f2bf(v1.y); o[6] = f2bf(v1.z); o[7] = f2bf(v1.w);
  ((u16x8*)(xb + (size_t)q * DD))[lane] = o;
#pragma unroll
  for (int m = 32; m; m >>= 1) s += __shfl_xor(s, m);
  if (lane == 0) x2[q] = s;
}

// ---- scan: segment starts, tile->class, per-hist-block scatter bases ----
__global__ void k_scan(int* __restrict__ meta) {
  __shared__ int h[CC], seg[CC], tile0[CC];
  int t = threadIdx.x;  // 128 threads
  if (t < CC) h[t] = meta[M_HIST + t];
  __syncthreads();
  if (t == 0) {
    int col = 0, nt = 0;
    for (int c = 0; c < CC; ++c) {
      seg[c] = col;
      tile0[c] = nt;
      int tiles = (h[c] + 127) >> 7;
      nt += tiles;
      col += tiles << 7;
    }
    meta[M_NT] = nt;
    meta[M_NCOL] = col;
  }
  __syncthreads();
  if (t < CC) {
    meta[M_SEG + t] = seg[t];
    int tiles = (h[t] + 127) >> 7;
    int t0 = tile0[t];
    for (int i = 0; i < tiles; ++i) meta[M_TC + t0 + i] = t;
    int run = seg[t];
    for (int bb = 0; bb < NHB; ++bb) {  // exclusive prefix over hist blocks
      meta[M_BB + bb * 128 + t] = run;
      run += meta[M_BH + bb * 128 + t];
    }
  }
}

// ---- scatter (rank via ballot-scan, NO atomics) + pad-fill + min-init ----
__global__ void k_spi(const float* __restrict__ db, const int* __restrict__ labels,
                      const int* __restrict__ meta, unsigned short* __restrict__ dbs,
                      float* __restrict__ db2s, unsigned* __restrict__ mb) {
  int b = blockIdx.x, t = threadIdx.x;
  if (b < (QN * CC) / 256) mb[b * 256 + t] = 0x7F800000u;  // +inf bits
  int w = t >> 6, lane = t & 63;
  if (b < NN / 4) {
    int n = b * 4 + w;
    int c = labels[n];
    // rank of n among same-class rows of its hist block (deterministic)
    int r0 = (n >> 10) << 10;
    int cnt = 0;
#pragma unroll
    for (int i = 0; i < 16; ++i) {
      int j = r0 + i * 64 + lane;
      unsigned long long bal = __ballot(j < n && labels[j] == c);
      cnt += __popcll(bal);
    }
    int pos = meta[M_BB + (n >> 10) * 128 + c] + cnt;
    const float4* row = (const float4*)(db + (size_t)n * DD);
    float4 v0 = row[lane * 2];
    float4 v1 = row[lane * 2 + 1];
    float s = v0.x * v0.x + v0.y * v0.y + v0.z * v0.z + v0.w * v0.w +
              v1.x * v1.x + v1.y * v1.y + v1.z * v1.z + v1.w * v1.w;
    u16x8 o;
    o[0] = f2bf(v0.x); o[1] = f2bf(v0.y); o[2] = f2bf(v0.z); o[3] = f2bf(v0.w);
    o[4] = f2bf(v1.x); o[5] = f2bf(v1.y); o[6] = f2bf(v1.z); o[7] = f2bf(v1.w);
    ((u16x8*)(dbs + (size_t)pos * DD))[lane] = o;
#pragma unroll
    for (int m = 32; m; m >>= 1) s += __shfl_xor(s, m);
    if (lane == 0) db2s[pos] = s;
  } else {
    int p = (b - NN / 4) * 4 + w;
    if (p >= meta[M_NCOL]) return;
    int c = meta[M_TC + (p >> 7)];
    if (p - meta[M_SEG + c] < meta[M_HIST + c]) return;  // real row
    u16x8 z = {0, 0, 0, 0, 0, 0, 0, 0};
    ((u16x8*)(dbs + (size_t)p * DD))[lane] = z;
    if (lane == 0) db2s[p] = __builtin_inff();
  }
}

// ---- fused bf16 MFMA GEMM + per-class row-min ----
// OCCUPANCY-FIRST: 128x128 tile, 8 waves of 64x32 (acc 4x2 = 32 AGPR),
// BK=64, SINGLE-buffered 32 KiB LDS -> 2 blocks/CU, target 16 waves/CU
// (launch_bounds 512,4). Plain stage->drain->compute loop (R3 pattern:
// the only structure that responded to anything in R3..R7, and it
// responded to TLP). 3-bit XOR swizzle both-sides (2-way = free, rule 21).
// XCD-chunked remap (T1).
__launch_bounds__(512, 4)
__global__ void k_gemm(const unsigned short* __restrict__ xb,
                       const unsigned short* __restrict__ dbs,
                       const float* __restrict__ x2, const float* __restrict__ db2s,
                       const int* __restrict__ meta, unsigned* __restrict__ minbits) {
  // XCD-aware bijective remap: 16 x 356 = 5696 blocks, 712 per XCD chunk.
  int flat = blockIdx.y * 16 + blockIdx.x;
  int swz = (flat & 7) * (16 * MAXTILES / 8) + (flat >> 3);
  int tq = swz & 15, tn = swz >> 4;
  if (tn >= meta[M_NT]) return;

  __shared__ __align__(16) unsigned short SA[128 * 64];  // 16 KiB
  __shared__ __align__(16) unsigned short SB[128 * 64];  // 16 KiB

  int t = threadIdx.x;
  int lane = t & 63;
  int wid = t >> 6;
  int wm = wid >> 2, wn = wid & 3;  // 2M x 4N waves; per-wave out 64 x 32
  int cl = lane & 15, g = lane >> 4;

  // staging: thread t -> rows t>>3 and 64+(t>>3), slot t&7 (linear LDS dest).
  // source granule pre-unswizzled: gsrc = slot ^ (row & 7)
  int gsrc = (t & 7) ^ ((t >> 3) & 7);
  const unsigned short* Asrc = xb + ((size_t)tq * 128 + (t >> 3)) * DD + gsrc * 8;
  const unsigned short* Bsrc = dbs + ((size_t)tn * 128 + (t >> 3)) * DD + gsrc * 8;
  int ldst = (t >> 3) * 64 + (t & 7) * 8;

  // read swizzle: phys granule = (kh*4+g) ^ (R&7); R&7 == cl&7 here
  int x3 = cl & 7;
  int gk0 = (g ^ x3) * 8;
  int gk1 = ((4 + g) ^ x3) * 8;
  int rowA[4], rowB[2];
#pragma unroll
  for (int m = 0; m < 4; ++m) rowA[m] = (wm * 64 + m * 16 + cl) * 64;
#pragma unroll
  for (int n = 0; n < 2; ++n) rowB[n] = (wn * 32 + n * 16 + cl) * 64;

  f32x4 acc[4][2];
#pragma unroll
  for (int m = 0; m < 4; ++m)
#pragma unroll
    for (int n = 0; n < 2; ++n) acc[m][n] = (f32x4){0.f, 0.f, 0.f, 0.f};

  for (int kt = 0; kt < DD / 64; ++kt) {
    int k0 = kt * 64;
    gload_lds16(Asrc + k0, &SA[ldst]);
    gload_lds16(Asrc + 64 * DD + k0, &SA[4096 + ldst]);
    gload_lds16(Bsrc + k0, &SB[ldst]);
    gload_lds16(Bsrc + 64 * DD + k0, &SB[4096 + ldst]);
    __syncthreads();  // drains vmcnt(0): tile ready for all waves

    // kh = 0
    {
      bf16x8 a0 = *(const bf16x8*)(&SA[rowA[0] + gk0]);
      bf16x8 a1 = *(const bf16x8*)(&SA[rowA[1] + gk0]);
      bf16x8 a2 = *(const bf16x8*)(&SA[rowA[2] + gk0]);
      bf16x8 a3 = *(const bf16x8*)(&SA[rowA[3] + gk0]);
      bf16x8 b0 = *(const bf16x8*)(&SB[rowB[0] + gk0]);
      bf16x8 b1 = *(const bf16x8*)(&SB[rowB[1] + gk0]);
      acc[0][0] = __builtin_amdgcn_mfma_f32_16x16x32_bf16(a0, b0, acc[0][0], 0, 0, 0);
      acc[0][1] = __builtin_amdgcn_mfma_f32_16x16x32_bf16(a0, b1, acc[0][1], 0, 0, 0);
      acc[1][0] = __builtin_amdgcn_mfma_f32_16x16x32_bf16(a1, b0, acc[1][0], 0, 0, 0);
      acc[1][1] = __builtin_amdgcn_mfma_f32_16x16x32_bf16(a1, b1, acc[1][1], 0, 0, 0);
      acc[2][0] = __builtin_amdgcn_mfma_f32_16x16x32_bf16(a2, b0, acc[2][0], 0, 0, 0);
      acc[2][1] = __builtin_amdgcn_mfma_f32_16x16x32_bf16(a2, b1, acc[2][1], 0, 0, 0);
      acc[3][0] = __builtin_amdgcn_mfma_f32_16x16x32_bf16(a3, b0, acc[3][0], 0, 0, 0);
      acc[3][1] = __builtin_amdgcn_mfma_f32_16x16x32_bf16(a3, b1, acc[3][1], 0, 0, 0);
    }
    // kh = 1
    {
      bf16x8 a0 = *(const bf16x8*)(&SA[rowA[0] + gk1]);
      bf16x8 a1 = *(const bf16x8*)(&SA[rowA[1] + gk1]);
      bf16x8 a2 = *(const bf16x8*)(&SA[rowA[2] + gk1]);
      bf16x8 a3 = *(const bf16x8*)(&SA[rowA[3] + gk1]);
      bf16x8 b0 = *(const bf16x8*)(&SB[rowB[0] + gk1]);
      bf16x8 b1 = *(const bf16x8*)(&SB[rowB[1] + gk1]);
      acc[0][0] = __builtin_amdgcn_mfma_f32_16x16x32_bf16(a0, b0, acc[0][0], 0, 0, 0);
      acc[0][1] = __builtin_amdgcn_mfma_f32_16x16x32_bf16(a0, b1, acc[0][1], 0, 0, 0);
      acc[1][0] = __builtin_amdgcn_mfma_f32_16x16x32_bf16(a1, b0, acc[1][0], 0, 0, 0);
      acc[1][1] = __builtin_amdgcn_mfma_f32_16x16x32_bf16(a1, b1, acc[1][1], 0, 0, 0);
      acc[2][0] = __builtin_amdgcn_mfma_f32_16x16x32_bf16(a2, b0, acc[2][0], 0, 0, 0);
      acc[2][1] = __builtin_amdgcn_mfma_f32_16x16x32_bf16(a2, b1, acc[2][1], 0, 0, 0);
      acc[3][0] = __builtin_amdgcn_mfma_f32_16x16x32_bf16(a3, b0, acc[3][0], 0, 0, 0);
      acc[3][1] = __builtin_amdgcn_mfma_f32_16x16x32_bf16(a3, b1, acc[3][1], 0, 0, 0);
    }
    __syncthreads();  // WAR: next kt overwrites the single buffer
  }

  // Epilogue: tile is one class. d2 = x2[q] + min_n(db2[n] - 2*dot).
  int cls = meta[M_TC + tn];
  float db2v[2];
#pragma unroll
  for (int n = 0; n < 2; ++n) db2v[n] = db2s[tn * 128 + wn * 32 + n * 16 + cl];

#pragma unroll
  for (int m = 0; m < 4; ++m) {
    int rowb = tq * 128 + wm * 64 + m * 16 + g * 4;
#pragma unroll
    for (int r = 0; r < 4; ++r) {
      float v = db2v[0] - 2.0f * acc[m][0][r];
      v = fminf(v, db2v[1] - 2.0f * acc[m][1][r]);
#pragma unroll
      for (int s = 1; s < 16; s <<= 1) v = fminf(v, __shfl_xor(v, s));
      if (cl == 0) {
        float d = sqrtf(fmaxf(x2[rowb + r] + v, 0.0f));
        atomicMin(minbits + (size_t)(rowb + r) * CC + cls, __float_as_uint(d));
      }
    }
  }
}

__global__ void k_final(const unsigned* __restrict__ mb, float* __restrict__ out) {
  int i = blockIdx.x * 256 + threadIdx.x;
  if (i < QN * CC) out[i] = -__uint_as_float(mb[i]);
}

extern "C" void kernel_launch(void* const* d_in, const int* in_sizes, int n_in,
                              void* d_out, int out_size, void* d_ws, size_t ws_size,
                              hipStream_t stream) {
  (void)in_sizes; (void)n_in; (void)out_size; (void)ws_size;
  const float* x = (const float*)d_in[0];
  const float* db = (const float*)d_in[1];
  const int* labels = (const int*)d_in[2];

  char* ws = (char*)d_ws;
  int* meta = (int*)ws;
  float* x2 = (float*)(ws + OFF_X2);
  float* db2s = (float*)(ws + OFF_DB2);
  unsigned* minbits = (unsigned*)(ws + OFF_MIN);
  unsigned short* xb = (unsigned short*)(ws + OFF_XB);
  unsigned short* dbs = (unsigned short*)(ws + OFF_DBS);

  hipMemsetAsync(ws, 0, 36864, stream);
  k_prep<<<QN / 4 + NHB, 256, 0, stream>>>(x, labels, xb, x2, meta);
  k_scan<<<1, 128, 0, stream>>>(meta);
  k_spi<<<NN / 4 + MAXNP / 4, 256, 0, stream>>>(db, labels, meta, dbs, db2s, minbits);
  k_gemm<<<dim3(16, MAXTILES), 512, 0, stream>>>(xb, dbs, x2, db2s, meta, minbits);
  k_final<<<(QN * CC + 255) / 256, 256, 0, stream>>>(minbits, (float*)d_out);
}

// Round 9
// 182.833 us; speedup vs baseline: 1.7235x; 1.3122x over previous
//
#include <hip/hip_runtime.h>

// Problem constants (reference: Q=2048, N=32768, D=512, C=100)
#define QN 2048
#define NN 32768
#define DD 512
#define CC 100
#define NG32 1184               // max 32-col groups: 32768/32 + 100 + slack
#define MAXTILES 296            // ceil(NG32*32/128)
#define NHB 32                  // label histogram blocks (NN/1024)

typedef float f32x4 __attribute__((ext_vector_type(4)));
typedef __bf16 bf16x8 __attribute__((ext_vector_type(8)));
typedef unsigned short u16x8 __attribute__((ext_vector_type(8)));

// meta layout (int32 indices; first 40 KiB of ws)
#define M_HIST 0     // [100] class histogram
#define M_SEG 128    // [100] class start col (32-aligned)
#define M_TC32 256   // [1184] class of each 32-col group (0 in padded tail)
#define M_NT 1504    // number of 128-col tiles
#define M_NCOL 1505  // nt*128 (padded col bound)
#define M_BH 1536    // [32][128] per-hist-block class counts
#define M_BB 5632    // [32][128] scatter base = seg[c] + prefix of counts

// ws byte offsets
#define OFF_X2 65536
#define OFF_DB2 131072
#define OFF_MIN (1u << 20)
#define OFF_XB (1u << 21)
#define OFF_DBS (1u << 22)

__device__ __forceinline__ unsigned short f2bf(float f) {
  unsigned u = __float_as_uint(f);
  unsigned r = 0x7FFFu + ((u >> 16) & 1u);  // round-to-nearest-even
  return (unsigned short)((u + r) >> 16);
}

typedef const __attribute__((address_space(1))) void* gptr_t;
typedef __attribute__((address_space(3))) void* lptr_t;
__device__ __forceinline__ void gload_lds16(const void* g, void* l) {
  __builtin_amdgcn_global_load_lds((gptr_t)g, (lptr_t)l, 16, 0, 0);
}

// ---- x: fp32->bf16 + row sumsq (blocks < QN/4); label hist (last 32) ----
__global__ void k_prep(const float* __restrict__ x, const int* __restrict__ labels,
                       unsigned short* __restrict__ xb, float* __restrict__ x2,
                       int* __restrict__ meta) {
  __shared__ int h[CC];
  int b = blockIdx.x, t = threadIdx.x;
  if (b >= QN / 4) {  // histogram part: block owns labels[bb*1024 .. +1023]
    int bb = b - QN / 4;
    if (t < CC) h[t] = 0;
    __syncthreads();
#pragma unroll
    for (int i = 0; i < 4; ++i) atomicAdd(&h[labels[bb * 1024 + i * 256 + t]], 1);
    __syncthreads();
    if (t < CC) {
      atomicAdd(&meta[M_HIST + t], h[t]);
      meta[M_BH + bb * 128 + t] = h[t];  // plain store, block owns the row
    }
    return;
  }
  int w = t >> 6, lane = t & 63;
  int q = b * 4 + w;
  const float4* row = (const float4*)(x + (size_t)q * DD);
  float4 v0 = row[lane * 2];
  float4 v1 = row[lane * 2 + 1];
  float s = v0.x * v0.x + v0.y * v0.y + v0.z * v0.z + v0.w * v0.w +
            v1.x * v1.x + v1.y * v1.y + v1.z * v1.z + v1.w * v1.w;
  u16x8 o;
  o[0] = f2bf(v0.x); o[1] = f2bf(v0.y); o[2] = f2bf(v0.z); o[3] = f2bf(v0.w);
  o[4] = f2bf(v1.x); o[5] = f2bf(v1.y); o[6] = f2bf(v1.z); o[7] = f2bf(v1.w);
  ((u16x8*)(xb + (size_t)q * DD))[lane] = o;
#pragma unroll
  for (int m = 32; m; m >>= 1) s += __shfl_xor(s, m);
  if (lane == 0) x2[q] = s;
}

// ---- scan: 32-aligned class starts, group->class, per-block scatter bases ----
__global__ void k_scan(int* __restrict__ meta) {
  __shared__ int h[CC], s32[CC];
  int t = threadIdx.x;  // 128 threads
  if (t < CC) h[t] = meta[M_HIST + t];
  __syncthreads();
  if (t == 0) {
    int col = 0;
    for (int c = 0; c < CC; ++c) {
      s32[c] = col;
      col += ((h[c] + 31) >> 5) << 5;  // pad each class to 32 cols
    }
    int nt = (col + 127) >> 7;
    meta[M_NT] = nt;
    meta[M_NCOL] = nt << 7;
  }
  __syncthreads();
  if (t < CC) {
    meta[M_SEG + t] = s32[t];
    int g0 = s32[t] >> 5, ng = (h[t] + 31) >> 5;
    for (int i = 0; i < ng; ++i) meta[M_TC32 + g0 + i] = t;
    int run = s32[t];
    for (int bb = 0; bb < NHB; ++bb) {  // exclusive prefix over hist blocks
      meta[M_BB + bb * 128 + t] = run;
      run += meta[M_BH + bb * 128 + t];
    }
  }
}

// ---- scatter (rank via ballot-scan, NO atomics) + pad-fill + min-init ----
__global__ void k_spi(const float* __restrict__ db, const int* __restrict__ labels,
                      const int* __restrict__ meta, unsigned short* __restrict__ dbs,
                      float* __restrict__ db2s, unsigned* __restrict__ mb) {
  int b = blockIdx.x, t = threadIdx.x;
  if (b < (QN * CC) / 256) mb[b * 256 + t] = 0x7F800000u;  // +inf bits
  int w = t >> 6, lane = t & 63;
  if (b < NN / 4) {
    int n = b * 4 + w;
    int c = labels[n];
    // rank of n among same-class rows of its hist block (deterministic)
    int r0 = (n >> 10) << 10;
    int cnt = 0;
#pragma unroll
    for (int i = 0; i < 16; ++i) {
      int j = r0 + i * 64 + lane;
      unsigned long long bal = __ballot(j < n && labels[j] == c);
      cnt += __popcll(bal);
    }
    int pos = meta[M_BB + (n >> 10) * 128 + c] + cnt;
    const float4* row = (const float4*)(db + (size_t)n * DD);
    float4 v0 = row[lane * 2];
    float4 v1 = row[lane * 2 + 1];
    float s = v0.x * v0.x + v0.y * v0.y + v0.z * v0.z + v0.w * v0.w +
              v1.x * v1.x + v1.y * v1.y + v1.z * v1.z + v1.w * v1.w;
    u16x8 o;
    o[0] = f2bf(v0.x); o[1] = f2bf(v0.y); o[2] = f2bf(v0.z); o[3] = f2bf(v0.w);
    o[4] = f2bf(v1.x); o[5] = f2bf(v1.y); o[6] = f2bf(v1.z); o[7] = f2bf(v1.w);
    ((u16x8*)(dbs + (size_t)pos * DD))[lane] = o;
#pragma unroll
    for (int m = 32; m; m >>= 1) s += __shfl_xor(s, m);
    if (lane == 0) db2s[pos] = s;
  } else {
    int p = (b - NN / 4) * 4 + w;
    if (p >= meta[M_NCOL]) return;
    int c = meta[M_TC32 + (p >> 5)];
    if (p - meta[M_SEG + c] < meta[M_HIST + c]) return;  // real row
    u16x8 z = {0, 0, 0, 0, 0, 0, 0, 0};
    ((u16x8*)(dbs + (size_t)p * DD))[lane] = z;
    if (lane == 0) db2s[p] = __builtin_inff();
  }
}

// ---- fused bf16 MFMA GEMM + per-class row-min ----
// 4-INDEPENDENT-BLOCKS/CU: 128x128 tile, BK=64, 4 waves of 64x64 (64 AGPR),
// 32 KiB single-buffer LDS, launch_bounds(256,4) => total regs <= 128 =>
// 4 resident blocks whose stage/compute phases stagger on the shared VMEM
// pipe (the binding resource per the R3..R8 model). Full unroll, literal
// kt offsets (no in-loop address math). 3-bit XOR swizzle both sides
// (0 conflicts in R5/R6). XCD-chunked remap.
__launch_bounds__(256, 4)
__global__ void k_gemm(const unsigned short* __restrict__ xb,
                       const unsigned short* __restrict__ dbs,
                       const float* __restrict__ x2, const float* __restrict__ db2s,
                       const int* __restrict__ meta, unsigned* __restrict__ minbits) {
  // XCD-aware bijective remap: 16 x 296 = 4736 blocks, 592 per XCD chunk.
  int flat = blockIdx.y * 16 + blockIdx.x;
  int swz = (flat & 7) * (16 * MAXTILES / 8) + (flat >> 3);
  int tq = swz & 15, tn = swz >> 4;
  if (tn >= meta[M_NT]) return;

  __shared__ __align__(16) unsigned short SA[128 * 64];  // 16 KiB
  __shared__ __align__(16) unsigned short SB[128 * 64];  // 16 KiB

  int t = threadIdx.x;
  int lane = t & 63;
  int wid = t >> 6;
  int wm = wid >> 1, wn = wid & 1;  // 2x2 waves of 64x64
  int cl = lane & 15, g = lane >> 4;

  // staging: thread t -> rows u*32 + (t>>3) (u=0..3), slot t&7, linear dest.
  // source granule pre-unswizzled: gsrc = slot ^ (row & 7)
  int trow = t >> 3;  // 0..31
  int gsrc = (t & 7) ^ (trow & 7);
  const unsigned short* Ag = xb + ((size_t)tq * 128 + trow) * DD + gsrc * 8;
  const unsigned short* Bg = dbs + ((size_t)tn * 128 + trow) * DD + gsrc * 8;
  int ldst = trow * 64 + (t & 7) * 8;

  // read swizzle: phys granule = (kh*4+g) ^ (R&7); R&7 == cl&7
  int x3 = cl & 7;
  int gk0 = ((0 + g) ^ x3) * 8;
  int gk1 = ((4 + g) ^ x3) * 8;
  int rowA[4], rowB[4];
#pragma unroll
  for (int m = 0; m < 4; ++m) rowA[m] = (wm * 64 + m * 16 + cl) * 64;
#pragma unroll
  for (int n = 0; n < 4; ++n) rowB[n] = (wn * 64 + n * 16 + cl) * 64;

  f32x4 acc[4][4];
#pragma unroll
  for (int m = 0; m < 4; ++m)
#pragma unroll
    for (int n = 0; n < 4; ++n) acc[m][n] = (f32x4){0.f, 0.f, 0.f, 0.f};

#pragma unroll
  for (int kt = 0; kt < 8; ++kt) {
    int k0 = kt * 64;  // literal after unroll -> folds into imm offsets
#pragma unroll
    for (int u = 0; u < 4; ++u) {
      gload_lds16(Ag + u * 32 * DD + k0, &SA[u * 2048 + ldst]);
      gload_lds16(Bg + u * 32 * DD + k0, &SB[u * 2048 + ldst]);
    }
    __syncthreads();  // drains own vmcnt; tile published

    {  // kh = 0
      bf16x8 a0 = *(const bf16x8*)(&SA[rowA[0] + gk0]);
      bf16x8 a1 = *(const bf16x8*)(&SA[rowA[1] + gk0]);
      bf16x8 a2 = *(const bf16x8*)(&SA[rowA[2] + gk0]);
      bf16x8 a3 = *(const bf16x8*)(&SA[rowA[3] + gk0]);
      bf16x8 b0 = *(const bf16x8*)(&SB[rowB[0] + gk0]);
      bf16x8 b1 = *(const bf16x8*)(&SB[rowB[1] + gk0]);
      bf16x8 b2 = *(const bf16x8*)(&SB[rowB[2] + gk0]);
      bf16x8 b3 = *(const bf16x8*)(&SB[rowB[3] + gk0]);
#pragma unroll
      for (int m = 0; m < 4; ++m) {
        bf16x8 a = (m == 0) ? a0 : (m == 1) ? a1 : (m == 2) ? a2 : a3;
        acc[m][0] = __builtin_amdgcn_mfma_f32_16x16x32_bf16(a, b0, acc[m][0], 0, 0, 0);
        acc[m][1] = __builtin_amdgcn_mfma_f32_16x16x32_bf16(a, b1, acc[m][1], 0, 0, 0);
        acc[m][2] = __builtin_amdgcn_mfma_f32_16x16x32_bf16(a, b2, acc[m][2], 0, 0, 0);
        acc[m][3] = __builtin_amdgcn_mfma_f32_16x16x32_bf16(a, b3, acc[m][3], 0, 0, 0);
      }
    }
    {  // kh = 1
      bf16x8 a0 = *(const bf16x8*)(&SA[rowA[0] + gk1]);
      bf16x8 a1 = *(const bf16x8*)(&SA[rowA[1] + gk1]);
      bf16x8 a2 = *(const bf16x8*)(&SA[rowA[2] + gk1]);
      bf16x8 a3 = *(const bf16x8*)(&SA[rowA[3] + gk1]);
      bf16x8 b0 = *(const bf16x8*)(&SB[rowB[0] + gk1]);
      bf16x8 b1 = *(const bf16x8*)(&SB[rowB[1] + gk1]);
      bf16x8 b2 = *(const bf16x8*)(&SB[rowB[2] + gk1]);
      bf16x8 b3 = *(const bf16x8*)(&SB[rowB[3] + gk1]);
#pragma unroll
      for (int m = 0; m < 4; ++m) {
        bf16x8 a = (m == 0) ? a0 : (m == 1) ? a1 : (m == 2) ? a2 : a3;
        acc[m][0] = __builtin_amdgcn_mfma_f32_16x16x32_bf16(a, b0, acc[m][0], 0, 0, 0);
        acc[m][1] = __builtin_amdgcn_mfma_f32_16x16x32_bf16(a, b1, acc[m][1], 0, 0, 0);
        acc[m][2] = __builtin_amdgcn_mfma_f32_16x16x32_bf16(a, b2, acc[m][2], 0, 0, 0);
        acc[m][3] = __builtin_amdgcn_mfma_f32_16x16x32_bf16(a, b3, acc[m][3], 0, 0, 0);
      }
    }
    __syncthreads();  // WAR: next kt overwrites the single buffer
  }

  // Epilogue: each 32-col half of the wave's 64 cols is one class.
  int gb = tn * 4 + wn * 2;
  int c0 = meta[M_TC32 + gb], c1 = meta[M_TC32 + gb + 1];
  float db2v[4];
#pragma unroll
  for (int n = 0; n < 4; ++n) db2v[n] = db2s[tn * 128 + wn * 64 + n * 16 + cl];

#pragma unroll
  for (int m = 0; m < 4; ++m) {
    int rowb = tq * 128 + wm * 64 + m * 16 + g * 4;
#pragma unroll
    for (int r = 0; r < 4; ++r) {
      float va = fminf(db2v[0] - 2.0f * acc[m][0][r], db2v[1] - 2.0f * acc[m][1][r]);
      float vb = fminf(db2v[2] - 2.0f * acc[m][2][r], db2v[3] - 2.0f * acc[m][3][r]);
#pragma unroll
      for (int s = 1; s < 16; s <<= 1) {
        va = fminf(va, __shfl_xor(va, s));
        vb = fminf(vb, __shfl_xor(vb, s));
      }
      if (cl == 0) {
        float xq = x2[rowb + r];
        float da = sqrtf(fmaxf(xq + va, 0.0f));
        float dbv = sqrtf(fmaxf(xq + vb, 0.0f));
        atomicMin(minbits + (size_t)(rowb + r) * CC + c0, __float_as_uint(da));
        atomicMin(minbits + (size_t)(rowb + r) * CC + c1, __float_as_uint(dbv));
      }
    }
  }
}

__global__ void k_final(const unsigned* __restrict__ mb, float* __restrict__ out) {
  int i = blockIdx.x * 256 + threadIdx.x;
  if (i < QN * CC) out[i] = -__uint_as_float(mb[i]);
}

extern "C" void kernel_launch(void* const* d_in, const int* in_sizes, int n_in,
                              void* d_out, int out_size, void* d_ws, size_t ws_size,
                              hipStream_t stream) {
  (void)in_sizes; (void)n_in; (void)out_size; (void)ws_size;
  const float* x = (const float*)d_in[0];
  const float* db = (const float*)d_in[1];
  const int* labels = (const int*)d_in[2];

  char* ws = (char*)d_ws;
  int* meta = (int*)ws;
  float* x2 = (float*)(ws + OFF_X2);
  float* db2s = (float*)(ws + OFF_DB2);
  unsigned* minbits = (unsigned*)(ws + OFF_MIN);
  unsigned short* xb = (unsigned short*)(ws + OFF_XB);
  unsigned short* dbs = (unsigned short*)(ws + OFF_DBS);

  hipMemsetAsync(ws, 0, 40960, stream);
  k_prep<<<QN / 4 + NHB, 256, 0, stream>>>(x, labels, xb, x2, meta);
  k_scan<<<1, 128, 0, stream>>>(meta);
  k_spi<<<NN / 4 + (MAXTILES * 128) / 4, 256, 0, stream>>>(db, labels, meta, dbs, db2s, minbits);
  k_gemm<<<dim3(16, MAXTILES), 256, 0, stream>>>(xb, dbs, x2, db2s, meta, minbits);
  k_final<<<(QN * CC + 255) / 256, 256, 0, stream>>>(minbits, (float*)d_out);
}

// Round 10
// 139.503 us; speedup vs baseline: 2.2588x; 1.3106x over previous
//
#include <hip/hip_runtime.h>

// Problem constants (reference: Q=2048, N=32768, D=512, C=100)
#define QN 2048
#define NN 32768
#define DD 512
#define CC 100
#define NG32 1124               // max 32-col groups: 32768/32 + 100
#define MAXTILES 282            // ceil(NG32*32/128)
#define NHB 32                  // label histogram blocks (NN/1024)

typedef float f32x4 __attribute__((ext_vector_type(4)));
typedef __bf16 bf16x8 __attribute__((ext_vector_type(8)));
typedef unsigned short u16x8 __attribute__((ext_vector_type(8)));

// meta layout (int32 indices; first 40 KiB of ws)
#define M_HIST 0     // [100] class histogram
#define M_SEG 128    // [100] class start col (32-aligned)
#define M_TC32 256   // [1184] class of each 32-col group (0 in padded tail)
#define M_NT 1504    // number of 128-col tiles
#define M_NCOL 1505  // total padded cols (32-aligned)
#define M_BH 1536    // [32][128] per-hist-block class counts
#define M_BB 5632    // [32][128] scatter base = seg[c] + prefix of counts

// ws byte offsets (all proven-fit: ends ~50.5 MB < R9's 50.9 MB footprint)
#define OFF_X2 65536u         // 8 KB
#define OFF_DB2 131072u       // <=144 KB
#define OFF_XB 524288u        // 2 MB
#define OFF_SLAB 3145728u     // <= 1128*2048*4 = 9.24 MB
#define OFF_DBS 13631488u     // <= 36096*512*2 = 36.96 MB

__device__ __forceinline__ unsigned short f2bf(float f) {
  unsigned u = __float_as_uint(f);
  unsigned r = 0x7FFFu + ((u >> 16) & 1u);  // round-to-nearest-even
  return (unsigned short)((u + r) >> 16);
}

typedef const __attribute__((address_space(1))) void* gptr_t;
typedef __attribute__((address_space(3))) void* lptr_t;
__device__ __forceinline__ void gload_lds16(const void* g, void* l) {
  __builtin_amdgcn_global_load_lds((gptr_t)g, (lptr_t)l, 16, 0, 0);
}

// ---- x: fp32->bf16 + row sumsq (blocks < QN/4); label hist (last 32) ----
__global__ void k_prep(const float* __restrict__ x, const int* __restrict__ labels,
                       unsigned short* __restrict__ xb, float* __restrict__ x2,
                       int* __restrict__ meta) {
  __shared__ int h[CC];
  int b = blockIdx.x, t = threadIdx.x;
  if (b >= QN / 4) {  // histogram part: block owns labels[bb*1024 .. +1023]
    int bb = b - QN / 4;
    if (t < CC) h[t] = 0;
    __syncthreads();
#pragma unroll
    for (int i = 0; i < 4; ++i) atomicAdd(&h[labels[bb * 1024 + i * 256 + t]], 1);
    __syncthreads();
    if (t < CC) {
      atomicAdd(&meta[M_HIST + t], h[t]);
      meta[M_BH + bb * 128 + t] = h[t];  // plain store, block owns the row
    }
    return;
  }
  int w = t >> 6, lane = t & 63;
  int q = b * 4 + w;
  const float4* row = (const float4*)(x + (size_t)q * DD);
  float4 v0 = row[lane * 2];
  float4 v1 = row[lane * 2 + 1];
  float s = v0.x * v0.x + v0.y * v0.y + v0.z * v0.z + v0.w * v0.w +
            v1.x * v1.x + v1.y * v1.y + v1.z * v1.z + v1.w * v1.w;
  u16x8 o;
  o[0] = f2bf(v0.x); o[1] = f2bf(v0.y); o[2] = f2bf(v0.z); o[3] = f2bf(v0.w);
  o[4] = f2bf(v1.x); o[5] = f2bf(v1.y); o[6] = f2bf(v1.z); o[7] = f2bf(v1.w);
  ((u16x8*)(xb + (size_t)q * DD))[lane] = o;
#pragma unroll
  for (int m = 32; m; m >>= 1) s += __shfl_xor(s, m);
  if (lane == 0) x2[q] = s;
}

// ---- scan: 32-aligned class starts, group->class, per-block scatter bases ----
__global__ void k_scan(int* __restrict__ meta) {
  __shared__ int h[CC], s32[CC];
  int t = threadIdx.x;  // 128 threads
  if (t < CC) h[t] = meta[M_HIST + t];
  __syncthreads();
  if (t == 0) {
    int col = 0;
    for (int c = 0; c < CC; ++c) {
      s32[c] = col;
      col += ((h[c] + 31) >> 5) << 5;  // pad each class to 32 cols
    }
    meta[M_NT] = (col + 127) >> 7;
    meta[M_NCOL] = col;
  }
  __syncthreads();
  if (t < CC) {
    meta[M_SEG + t] = s32[t];
    int g0 = s32[t] >> 5, ng = (h[t] + 31) >> 5;
    for (int i = 0; i < ng; ++i) meta[M_TC32 + g0 + i] = t;
    int run = s32[t];
    for (int bb = 0; bb < NHB; ++bb) {  // exclusive prefix over hist blocks
      meta[M_BB + bb * 128 + t] = run;
      run += meta[M_BH + bb * 128 + t];
    }
  }
}

// ---- scatter (rank via ballot-scan, NO atomics) + pad-fill ----
__global__ void k_spi(const float* __restrict__ db, const int* __restrict__ labels,
                      const int* __restrict__ meta, unsigned short* __restrict__ dbs,
                      float* __restrict__ db2s) {
  int b = blockIdx.x, t = threadIdx.x;
  int w = t >> 6, lane = t & 63;
  if (b < NN / 4) {
    int n = b * 4 + w;
    int c = labels[n];
    // rank of n among same-class rows of its hist block (deterministic)
    int r0 = (n >> 10) << 10;
    int cnt = 0;
#pragma unroll
    for (int i = 0; i < 16; ++i) {
      int j = r0 + i * 64 + lane;
      unsigned long long bal = __ballot(j < n && labels[j] == c);
      cnt += __popcll(bal);
    }
    int pos = meta[M_BB + (n >> 10) * 128 + c] + cnt;
    const float4* row = (const float4*)(db + (size_t)n * DD);
    float4 v0 = row[lane * 2];
    float4 v1 = row[lane * 2 + 1];
    float s = v0.x * v0.x + v0.y * v0.y + v0.z * v0.z + v0.w * v0.w +
              v1.x * v1.x + v1.y * v1.y + v1.z * v1.z + v1.w * v1.w;
    u16x8 o;
    o[0] = f2bf(v0.x); o[1] = f2bf(v0.y); o[2] = f2bf(v0.z); o[3] = f2bf(v0.w);
    o[4] = f2bf(v1.x); o[5] = f2bf(v1.y); o[6] = f2bf(v1.z); o[7] = f2bf(v1.w);
    ((u16x8*)(dbs + (size_t)pos * DD))[lane] = o;
#pragma unroll
    for (int m = 32; m; m >>= 1) s += __shfl_xor(s, m);
    if (lane == 0) db2s[pos] = s;
  } else {
    int p = (b - NN / 4) * 4 + w;
    if (p >= meta[M_NCOL]) return;
    int c = meta[M_TC32 + (p >> 5)];
    if (p - meta[M_SEG + c] < meta[M_HIST + c]) return;  // real row
    u16x8 z = {0, 0, 0, 0, 0, 0, 0, 0};
    ((u16x8*)(dbs + (size_t)p * DD))[lane] = z;
    if (lane == 0) db2s[p] = __builtin_inff();
  }
}

// ---- fused bf16 MFMA GEMM + per-group row-min -> slab (NO atomics) ----
// R9's winning core kept verbatim: 128x128 tile, BK=64, 4 waves of 64x64
// (64 AGPR), 32 KiB single-buffer LDS, launch_bounds(256,4) -> 4 resident
// independent blocks/CU staggering on the VMEM pipe. 3-bit XOR swizzle both
// sides (0 conflicts). XCD-chunked remap. NEW: epilogue stores partial
// min(db2 - 2*dot) per (32-col group, row) to a race-free slab — sqrt/x2
// deferred to k_final (min is monotone), 2.2M device atomics eliminated.
__launch_bounds__(256, 4)
__global__ void k_gemm(const unsigned short* __restrict__ xb,
                       const unsigned short* __restrict__ dbs,
                       const float* __restrict__ db2s,
                       const int* __restrict__ meta, float* __restrict__ slab) {
  // XCD-aware bijective remap: 16 x 282 = 4512 blocks, 564 per XCD chunk.
  int flat = blockIdx.y * 16 + blockIdx.x;
  int swz = (flat & 7) * (16 * MAXTILES / 8) + (flat >> 3);
  int tq = swz & 15, tn = swz >> 4;
  if (tn >= meta[M_NT]) return;

  __shared__ __align__(16) unsigned short SA[128 * 64];  // 16 KiB
  __shared__ __align__(16) unsigned short SB[128 * 64];  // 16 KiB

  int t = threadIdx.x;
  int lane = t & 63;
  int wid = t >> 6;
  int wm = wid >> 1, wn = wid & 1;  // 2x2 waves of 64x64
  int cl = lane & 15, g = lane >> 4;

  // staging: thread t -> rows u*32 + (t>>3) (u=0..3), slot t&7, linear dest.
  // source granule pre-unswizzled: gsrc = slot ^ (row & 7)
  int trow = t >> 3;  // 0..31
  int gsrc = (t & 7) ^ (trow & 7);
  const unsigned short* Ag = xb + ((size_t)tq * 128 + trow) * DD + gsrc * 8;
  const unsigned short* Bg = dbs + ((size_t)tn * 128 + trow) * DD + gsrc * 8;
  int ldst = trow * 64 + (t & 7) * 8;

  // read swizzle: phys granule = (kh*4+g) ^ (R&7); R&7 == cl&7
  int x3 = cl & 7;
  int gk0 = ((0 + g) ^ x3) * 8;
  int gk1 = ((4 + g) ^ x3) * 8;
  int rowA[4], rowB[4];
#pragma unroll
  for (int m = 0; m < 4; ++m) rowA[m] = (wm * 64 + m * 16 + cl) * 64;
#pragma unroll
  for (int n = 0; n < 4; ++n) rowB[n] = (wn * 64 + n * 16 + cl) * 64;

  f32x4 acc[4][4];
#pragma unroll
  for (int m = 0; m < 4; ++m)
#pragma unroll
    for (int n = 0; n < 4; ++n) acc[m][n] = (f32x4){0.f, 0.f, 0.f, 0.f};

#pragma unroll
  for (int kt = 0; kt < 8; ++kt) {
    int k0 = kt * 64;  // literal after unroll -> folds into imm offsets
#pragma unroll
    for (int u = 0; u < 4; ++u) {
      gload_lds16(Ag + u * 32 * DD + k0, &SA[u * 2048 + ldst]);
      gload_lds16(Bg + u * 32 * DD + k0, &SB[u * 2048 + ldst]);
    }
    __syncthreads();  // drains own vmcnt; tile published

    {  // kh = 0
      bf16x8 a0 = *(const bf16x8*)(&SA[rowA[0] + gk0]);
      bf16x8 a1 = *(const bf16x8*)(&SA[rowA[1] + gk0]);
      bf16x8 a2 = *(const bf16x8*)(&SA[rowA[2] + gk0]);
      bf16x8 a3 = *(const bf16x8*)(&SA[rowA[3] + gk0]);
      bf16x8 b0 = *(const bf16x8*)(&SB[rowB[0] + gk0]);
      bf16x8 b1 = *(const bf16x8*)(&SB[rowB[1] + gk0]);
      bf16x8 b2 = *(const bf16x8*)(&SB[rowB[2] + gk0]);
      bf16x8 b3 = *(const bf16x8*)(&SB[rowB[3] + gk0]);
#pragma unroll
      for (int m = 0; m < 4; ++m) {
        bf16x8 a = (m == 0) ? a0 : (m == 1) ? a1 : (m == 2) ? a2 : a3;
        acc[m][0] = __builtin_amdgcn_mfma_f32_16x16x32_bf16(a, b0, acc[m][0], 0, 0, 0);
        acc[m][1] = __builtin_amdgcn_mfma_f32_16x16x32_bf16(a, b1, acc[m][1], 0, 0, 0);
        acc[m][2] = __builtin_amdgcn_mfma_f32_16x16x32_bf16(a, b2, acc[m][2], 0, 0, 0);
        acc[m][3] = __builtin_amdgcn_mfma_f32_16x16x32_bf16(a, b3, acc[m][3], 0, 0, 0);
      }
    }
    {  // kh = 1
      bf16x8 a0 = *(const bf16x8*)(&SA[rowA[0] + gk1]);
      bf16x8 a1 = *(const bf16x8*)(&SA[rowA[1] + gk1]);
      bf16x8 a2 = *(const bf16x8*)(&SA[rowA[2] + gk1]);
      bf16x8 a3 = *(const bf16x8*)(&SA[rowA[3] + gk1]);
      bf16x8 b0 = *(const bf16x8*)(&SB[rowB[0] + gk1]);
      bf16x8 b1 = *(const bf16x8*)(&SB[rowB[1] + gk1]);
      bf16x8 b2 = *(const bf16x8*)(&SB[rowB[2] + gk1]);
      bf16x8 b3 = *(const bf16x8*)(&SB[rowB[3] + gk1]);
#pragma unroll
      for (int m = 0; m < 4; ++m) {
        bf16x8 a = (m == 0) ? a0 : (m == 1) ? a1 : (m == 2) ? a2 : a3;
        acc[m][0] = __builtin_amdgcn_mfma_f32_16x16x32_bf16(a, b0, acc[m][0], 0, 0, 0);
        acc[m][1] = __builtin_amdgcn_mfma_f32_16x16x32_bf16(a, b1, acc[m][1], 0, 0, 0);
        acc[m][2] = __builtin_amdgcn_mfma_f32_16x16x32_bf16(a, b2, acc[m][2], 0, 0, 0);
        acc[m][3] = __builtin_amdgcn_mfma_f32_16x16x32_bf16(a, b3, acc[m][3], 0, 0, 0);
      }
    }
    __syncthreads();  // WAR: next kt overwrites the single buffer
  }

  // Epilogue: per (32-col group, row) partial min of (db2 - 2*dot) -> slab.
  // No x2, no sqrt, no atomics (min is monotone; each cell written once).
  int gb = tn * 4 + wn * 2;
  float db2v[4];
#pragma unroll
  for (int n = 0; n < 4; ++n) db2v[n] = db2s[tn * 128 + wn * 64 + n * 16 + cl];

#pragma unroll
  for (int m = 0; m < 4; ++m) {
    f32x4 va4, vb4;
#pragma unroll
    for (int r = 0; r < 4; ++r) {
      float va = fminf(db2v[0] - 2.0f * acc[m][0][r], db2v[1] - 2.0f * acc[m][1][r]);
      float vb = fminf(db2v[2] - 2.0f * acc[m][2][r], db2v[3] - 2.0f * acc[m][3][r]);
#pragma unroll
      for (int s = 1; s < 16; s <<= 1) {
        va = fminf(va, __shfl_xor(va, s));
        vb = fminf(vb, __shfl_xor(vb, s));
      }
      va4[r] = va;
      vb4[r] = vb;
    }
    if (cl == 0) {  // lanes 0,16,32,48: one float4 per g-group of 4 rows
      int row0 = tq * 128 + wm * 64 + m * 16 + g * 4;
      *(f32x4*)(slab + (size_t)gb * QN + row0) = va4;
      *(f32x4*)(slab + (size_t)(gb + 1) * QN + row0) = vb4;
    }
  }
}

// ---- final: per (q, class) min over the class's groups; add x2, sqrt ----
__global__ void k_final(const int* __restrict__ meta, const float* __restrict__ slab,
                        const float* __restrict__ x2, float* __restrict__ out) {
  int c = blockIdx.y;
  int q = blockIdx.x * 256 + threadIdx.x;
  int g0 = meta[M_SEG + c] >> 5;
  int ng = (meta[M_HIST + c] + 31) >> 5;
  float v = __builtin_inff();
  const float* p = slab + (size_t)g0 * QN + q;
  for (int i = 0; i < ng; ++i) v = fminf(v, p[(size_t)i * QN]);
  out[(size_t)q * CC + c] = -sqrtf(fmaxf(x2[q] + v, 0.0f));
}

extern "C" void kernel_launch(void* const* d_in, const int* in_sizes, int n_in,
                              void* d_out, int out_size, void* d_ws, size_t ws_size,
                              hipStream_t stream) {
  (void)in_sizes; (void)n_in; (void)out_size; (void)ws_size;
  const float* x = (const float*)d_in[0];
  const float* db = (const float*)d_in[1];
  const int* labels = (const int*)d_in[2];

  char* ws = (char*)d_ws;
  int* meta = (int*)ws;
  float* x2 = (float*)(ws + OFF_X2);
  float* db2s = (float*)(ws + OFF_DB2);
  float* slab = (float*)(ws + OFF_SLAB);
  unsigned short* xb = (unsigned short*)(ws + OFF_XB);
  unsigned short* dbs = (unsigned short*)(ws + OFF_DBS);

  hipMemsetAsync(ws, 0, 40960, stream);
  k_prep<<<QN / 4 + NHB, 256, 0, stream>>>(x, labels, xb, x2, meta);
  k_scan<<<1, 128, 0, stream>>>(meta);
  k_spi<<<NN / 4 + (MAXTILES * 128) / 4, 256, 0, stream>>>(db, labels, meta, dbs, db2s);
  k_gemm<<<dim3(16, MAXTILES), 256, 0, stream>>>(xb, dbs, db2s, meta, slab);
  k_final<<<dim3(QN / 256, CC), 256, 0, stream>>>(meta, slab, x2, (float*)d_out);
}